// Round 2
// baseline (89.496 us; speedup 1.0000x reference)
//
#include <hip/hip_runtime.h>
#include <hip/hip_bf16.h>

typedef __attribute__((ext_vector_type(8))) short s16x8;
typedef __attribute__((ext_vector_type(4))) float f32x4;

constexpr int NB = 8, CI = 256, OC = 256, HH = 64, WW = 64, HP = 66, WP = 66;
constexpr int NBASES = 5;
constexpr int WELEMS = OC * CI * 9;      // 589824 per basis
constexpr int BM = 128, BN = 128, BK = 32;
constexpr int NT = 9 * (CI / BK);        // 72 K-steps (tap-major, then channel chunk)

static __device__ __forceinline__ unsigned short f2bf(float f) {
    unsigned int u = __builtin_bit_cast(unsigned int, f);
    unsigned int r = (u + 0x7fffu + ((u >> 16) & 1u)) >> 16;   // RNE
    return (unsigned short)r;
}

// ---- 1) per-basis partial sums of |w| : grid 5*64, block 256 ----
__global__ void k_abs_partial(const float* __restrict__ w, float* __restrict__ part) {
    int b = blockIdx.x >> 6, chunk = blockIdx.x & 63;
    const float4* v = (const float4*)(w + (size_t)b * WELEMS + (size_t)chunk * (WELEMS / 64));
    float s = 0.f;
    for (int i = threadIdx.x; i < WELEMS / 64 / 4; i += 256) {
        float4 t = v[i];
        s += fabsf(t.x) + fabsf(t.y) + fabsf(t.z) + fabsf(t.w);
    }
    #pragma unroll
    for (int off = 32; off; off >>= 1) s += __shfl_down(s, off, 64);
    __shared__ float ls[4];
    int lane = threadIdx.x & 63, wid = threadIdx.x >> 6;
    if (lane == 0) ls[wid] = s;
    __syncthreads();
    if (threadIdx.x == 0) part[blockIdx.x] = ls[0] + ls[1] + ls[2] + ls[3];
}

// ---- 2) wsum[tap][o][i] = (1/5) * sum_b sign(w[b,o,i,tap])*s_b, bf16 ----
// (scale finalization fused: wave 0 reduces the 320 partials; grid OC, block 256)
__global__ void k_wsum(const float* __restrict__ w, const float* __restrict__ part,
                       unsigned short* __restrict__ wsum) {
    __shared__ float sLDS[NBASES];
    int tid = threadIdx.x;
    if (tid < 64) {
        #pragma unroll
        for (int b = 0; b < NBASES; ++b) {
            float v = part[b * 64 + tid];
            #pragma unroll
            for (int off = 32; off; off >>= 1) v += __shfl_down(v, off, 64);
            if (tid == 0) sLDS[b] = v * (1.0f / (float)WELEMS);
        }
    }
    __syncthreads();
    float sc[NBASES];
    #pragma unroll
    for (int b = 0; b < NBASES; ++b) sc[b] = sLDS[b];

    int o = blockIdx.x, i = tid;
    const float* base = w + ((size_t)(o * CI + i)) * 9;
    float acc[9];
    #pragma unroll
    for (int t = 0; t < 9; ++t) acc[t] = 0.f;
    #pragma unroll
    for (int b = 0; b < NBASES; ++b) {
        const float* wb = base + (size_t)b * WELEMS;
        #pragma unroll
        for (int t = 0; t < 9; ++t) {
            float xv = wb[t];
            acc[t] += (xv > 0.f) ? sc[b] : ((xv < 0.f) ? -sc[b] : 0.f);
        }
    }
    #pragma unroll
    for (int t = 0; t < 9; ++t)
        wsum[(t * OC + o) * CI + i] = f2bf(acc[t] * 0.2f);
}

// ---- 3) xq_pad[n][h+1][w+1][c] = bf16(round(clip(x[n][c][h][w],0,1))), borders 0 ----
// grid NB*HH (one (n,h) row per block), block 256
__global__ void k_quant(const float* __restrict__ x, unsigned short* __restrict__ xq) {
    __shared__ unsigned short tile[64][264];   // 264 = 8*33 keeps 16B-aligned rows
    int nh = blockIdx.x, n = nh >> 6, h = nh & 63;
    const float* xb = x + ((size_t)n * CI) * (HH * WW) + h * WW;   // + c*4096 + w
    int tw = threadIdx.x & 63, tc0 = threadIdx.x >> 6;
    for (int c = tc0; c < CI; c += 4) {
        float v = xb[(size_t)c * (HH * WW) + tw];
        v = rintf(fminf(fmaxf(v, 0.f), 1.f));
        tile[tw][c] = f2bf(v);
    }
    __syncthreads();
    unsigned short* ob = xq + ((size_t)(n * HP + (h + 1)) * WP + 1) * CI;
    int wq = threadIdx.x >> 5;            // 0..7
    int cq = (threadIdx.x & 31) * 8;      // 0..248
    #pragma unroll
    for (int i = 0; i < 8; ++i) {
        int wv = i * 8 + wq;
        s16x8 v = *(const s16x8*)&tile[wv][cq];
        *(s16x8*)(ob + wv * CI + cq) = v;
    }
    // zero the two side border cells of this padded row (w_p = 0 and 65)
    (ob - CI)[threadIdx.x] = 0;
    (ob + 64 * CI)[threadIdx.x] = 0;
    // blocks at h==0 / h==63 zero the full top/bottom padded rows of this n
    if (h == 0) {
        unsigned short* r0 = xq + ((size_t)(n * HP + 0) * WP) * CI;
        for (int i = threadIdx.x; i < WP * CI; i += 256) r0[i] = 0;
    }
    if (h == HH - 1) {
        unsigned short* r65 = xq + ((size_t)(n * HP + (HP - 1)) * WP) * CI;
        for (int i = threadIdx.x; i < WP * CI; i += 256) r65[i] = 0;
    }
}

// ---- 4) implicit-GEMM conv, 2-phase pipelined (T3+T4): 128 px x 128 oc, BK=32 ----
__launch_bounds__(256, 2)
__global__ void k_conv(const unsigned short* __restrict__ xq,
                       const unsigned short* __restrict__ wsum,
                       float* __restrict__ out) {
    __shared__ __align__(16) unsigned short lA[2][BM * BK];  // 2 x 8 KB
    __shared__ __align__(16) unsigned short lB[2][BN * BK];  // 2 x 8 KB

    int bx = blockIdx.x;
    int pt = bx >> 1, ot = bx & 1;
    int pb = pt * BM;                  // first pixel (n*4096 + h*64 + w)
    int n = pb >> 12;
    int h0 = (pb >> 6) & 63;           // even; LDS rows 0..63 -> h0, 64..127 -> h0+1
    int oc0 = ot * BN;
    int tid = threadIdx.x;

    int base0 = (n * HP + h0) * WP * CI;   // A base (padded coords), + (kh*WP+kw)*CI per tap
    int bBase0 = oc0 * CI;

    // staging: chunk q in [0,512): row=q>>2, s'=q&3, fetch global slot = s'^((row>>1)&3)
    int aOff[2], bOff[2];
    #pragma unroll
    for (int k = 0; k < 2; ++k) {
        int q = tid + k * 256;
        int row = q >> 2, sp = q & 3;
        int slot = sp ^ ((row >> 1) & 3);
        aOff[k] = (((row >> 6) * WP) + (row & 63)) * CI + slot * 8;
        bOff[k] = row * CI + slot * 8;
    }
    // fragment LDS offsets (elems): row r, kslot g lives at s' = g ^ ((r>>1)&3)
    int lane = tid & 63, wid = tid >> 6;
    int wy = wid & 1, wx = wid >> 1;
    int g = lane >> 4, r16 = lane & 15;
    int fA[4], fB[4];
    #pragma unroll
    for (int m = 0; m < 4; ++m) {
        int ra = wy * 64 + m * 16 + r16;
        fA[m] = ra * BK + (g ^ ((ra >> 1) & 3)) * 8;
        int rb = wx * 64 + m * 16 + r16;
        fB[m] = rb * BK + (g ^ ((rb >> 1) & 3)) * 8;
    }

    f32x4 acc[4][4] = {};

    auto stage = [&](int t) {
        int buf = t & 1;
        int tap = t >> 3;
        int c0 = (t & 7) << 5;
        int kh = (tap * 171) >> 9;         // tap/3 for tap in [0,9)
        int kw = tap - kh * 3;
        const unsigned short* aSrc = xq + base0 + (kh * WP + kw) * CI + c0;
        const unsigned short* bSrc = wsum + tap * (OC * CI) + bBase0 + c0;
        #pragma unroll
        for (int k = 0; k < 2; ++k) {
            int q = tid + k * 256;
            __builtin_amdgcn_global_load_lds(
                (const __attribute__((address_space(1))) void*)(aSrc + aOff[k]),
                (__attribute__((address_space(3))) void*)(&lA[buf][q * 8]), 16, 0, 0);
            __builtin_amdgcn_global_load_lds(
                (const __attribute__((address_space(1))) void*)(bSrc + bOff[k]),
                (__attribute__((address_space(3))) void*)(&lB[buf][q * 8]), 16, 0, 0);
        }
    };

    auto compute = [&](int t) {
        int buf = t & 1;
        s16x8 af[4], bfr[4];
        #pragma unroll
        for (int m = 0; m < 4; ++m) af[m] = *(const s16x8*)&lA[buf][fA[m]];
        #pragma unroll
        for (int m = 0; m < 4; ++m) bfr[m] = *(const s16x8*)&lB[buf][fB[m]];
        #pragma unroll
        for (int m = 0; m < 4; ++m)
            #pragma unroll
            for (int nn = 0; nn < 4; ++nn)
                acc[m][nn] = __builtin_amdgcn_mfma_f32_16x16x32_bf16(
                    af[m], bfr[nn], acc[m][nn], 0, 0, 0);
    };

    // prologue: fill buf0 (4 loads in flight)
    stage(0);
    #pragma unroll 1
    for (int t = 0; t < NT - 1; ++t) {
        stage(t + 1);                                   // 4 newer loads in flight
        asm volatile("s_waitcnt vmcnt(4)" ::: "memory"); // tile t's 4 loads landed
        __builtin_amdgcn_s_barrier();                    // all waves: buf[t&1] ready
        compute(t);
        asm volatile("s_waitcnt lgkmcnt(0)" ::: "memory"); // my reads of buf[t&1] done
        __builtin_amdgcn_s_barrier();                    // safe to overwrite buf[t&1]
    }
    asm volatile("s_waitcnt vmcnt(0)" ::: "memory");
    __builtin_amdgcn_s_barrier();
    compute(NT - 1);

    // epilogue: C/D 16x16: col=lane&15 (oc), row=(lane>>4)*4+reg (pixel)
    int hw0 = pb & 4095;
    #pragma unroll
    for (int m = 0; m < 4; ++m) {
        int pl = wy * 64 + m * 16 + g * 4;
        #pragma unroll
        for (int nn = 0; nn < 4; ++nn) {
            int oc = oc0 + wx * 64 + nn * 16 + r16;
            float4 v;
            v.x = acc[m][nn][0]; v.y = acc[m][nn][1];
            v.z = acc[m][nn][2]; v.w = acc[m][nn][3];
            *(float4*)(out + ((size_t)(n * OC + oc) << 12) + hw0 + pl) = v;
        }
    }
}

extern "C" void kernel_launch(void* const* d_in, const int* in_sizes, int n_in,
                              void* d_out, int out_size, void* d_ws, size_t ws_size,
                              hipStream_t stream) {
    (void)in_sizes; (void)n_in; (void)out_size; (void)ws_size;
    const float* x   = (const float*)d_in[0];
    const float* wts = (const float*)d_in[1];
    float* out = (float*)d_out;
    char* wsb = (char*)d_ws;
    float* part            = (float*)wsb;                 // 320 floats
    unsigned short* wsum   = (unsigned short*)(wsb + 4096);          // 9*256*256 bf16 = 1.125 MiB
    unsigned short* xq     = (unsigned short*)(wsb + (size_t)(2u << 20)); // 8*66*66*256 bf16 ~ 17 MiB

    hipLaunchKernelGGL(k_abs_partial, dim3(NBASES * 64), dim3(256), 0, stream, wts, part);
    hipLaunchKernelGGL(k_wsum,        dim3(OC),          dim3(256), 0, stream, wts, part, wsum);
    hipLaunchKernelGGL(k_quant,       dim3(NB * HH),     dim3(256), 0, stream, x, xq);
    hipLaunchKernelGGL(k_conv, dim3((NB * HH * WW / BM) * (OC / BN)), dim3(256), 0, stream,
                       xq, wsum, out);
}

// Round 3
// 83.301 us; speedup vs baseline: 1.0744x; 1.0744x over previous
//
#include <hip/hip_runtime.h>
#include <hip/hip_bf16.h>

typedef __attribute__((ext_vector_type(8))) short s16x8;
typedef __attribute__((ext_vector_type(4))) float f32x4;

constexpr int NB = 8, CI = 256, OC = 256, HH = 64, WW = 64, HP = 66, WP = 66;
constexpr int NBASES = 5;
constexpr int WELEMS = OC * CI * 9;      // 589824 per basis
constexpr int BM = 128, BN = 128, BK = 32;
constexpr int NT = 9 * (CI / BK);        // 72 K-steps (tap-major, then channel chunk)

static __device__ __forceinline__ unsigned short f2bf(float f) {
    unsigned int u = __builtin_bit_cast(unsigned int, f);
    unsigned int r = (u + 0x7fffu + ((u >> 16) & 1u)) >> 16;   // RNE
    return (unsigned short)r;
}

// ---- 1) per-basis partial sums of |w| : grid 5*64, block 256 ----
__global__ void k_abs_partial(const float* __restrict__ w, float* __restrict__ part) {
    int b = blockIdx.x >> 6, chunk = blockIdx.x & 63;
    const float4* v = (const float4*)(w + (size_t)b * WELEMS + (size_t)chunk * (WELEMS / 64));
    float s = 0.f;
    for (int i = threadIdx.x; i < WELEMS / 64 / 4; i += 256) {
        float4 t = v[i];
        s += fabsf(t.x) + fabsf(t.y) + fabsf(t.z) + fabsf(t.w);
    }
    #pragma unroll
    for (int off = 32; off; off >>= 1) s += __shfl_down(s, off, 64);
    __shared__ float ls[4];
    int lane = threadIdx.x & 63, wid = threadIdx.x >> 6;
    if (lane == 0) ls[wid] = s;
    __syncthreads();
    if (threadIdx.x == 0) part[blockIdx.x] = ls[0] + ls[1] + ls[2] + ls[3];
}

// ---- 2) wsum[tap][o][i] = (1/5) * sum_b sign(w[b,o,i,tap])*s_b, bf16 ----
// (scale finalization fused: wave 0 reduces the 320 partials; grid OC, block 256)
__global__ void k_wsum(const float* __restrict__ w, const float* __restrict__ part,
                       unsigned short* __restrict__ wsum) {
    __shared__ float sLDS[NBASES];
    int tid = threadIdx.x;
    if (tid < 64) {
        #pragma unroll
        for (int b = 0; b < NBASES; ++b) {
            float v = part[b * 64 + tid];
            #pragma unroll
            for (int off = 32; off; off >>= 1) v += __shfl_down(v, off, 64);
            if (tid == 0) sLDS[b] = v * (1.0f / (float)WELEMS);
        }
    }
    __syncthreads();
    float sc[NBASES];
    #pragma unroll
    for (int b = 0; b < NBASES; ++b) sc[b] = sLDS[b];

    int o = blockIdx.x, i = tid;
    const float* base = w + ((size_t)(o * CI + i)) * 9;
    float acc[9];
    #pragma unroll
    for (int t = 0; t < 9; ++t) acc[t] = 0.f;
    #pragma unroll
    for (int b = 0; b < NBASES; ++b) {
        const float* wb = base + (size_t)b * WELEMS;
        #pragma unroll
        for (int t = 0; t < 9; ++t) {
            float xv = wb[t];
            acc[t] += (xv > 0.f) ? sc[b] : ((xv < 0.f) ? -sc[b] : 0.f);
        }
    }
    #pragma unroll
    for (int t = 0; t < 9; ++t)
        wsum[(t * OC + o) * CI + i] = f2bf(acc[t] * 0.2f);
}

// ---- 3) xq_pad[n][h+1][w+1][c] = bf16(round(clip(x[n][c][h][w],0,1))), borders 0 ----
// grid NB*HH (one (n,h) row per block), block 256
__global__ void k_quant(const float* __restrict__ x, unsigned short* __restrict__ xq) {
    __shared__ unsigned short tile[64][264];   // 264 = 8*33 keeps 16B-aligned rows
    int nh = blockIdx.x, n = nh >> 6, h = nh & 63;
    const float* xb = x + ((size_t)n * CI) * (HH * WW) + h * WW;   // + c*4096 + w
    int tw = threadIdx.x & 63, tc0 = threadIdx.x >> 6;
    for (int c = tc0; c < CI; c += 4) {
        float v = xb[(size_t)c * (HH * WW) + tw];
        v = rintf(fminf(fmaxf(v, 0.f), 1.f));
        tile[tw][c] = f2bf(v);
    }
    __syncthreads();
    unsigned short* ob = xq + ((size_t)(n * HP + (h + 1)) * WP + 1) * CI;
    int wq = threadIdx.x >> 5;            // 0..7
    int cq = (threadIdx.x & 31) * 8;      // 0..248
    #pragma unroll
    for (int i = 0; i < 8; ++i) {
        int wv = i * 8 + wq;
        s16x8 v = *(const s16x8*)&tile[wv][cq];
        *(s16x8*)(ob + wv * CI + cq) = v;
    }
    // zero the two side border cells of this padded row (w_p = 0 and 65)
    (ob - CI)[threadIdx.x] = 0;
    (ob + 64 * CI)[threadIdx.x] = 0;
    // blocks at h==0 / h==63 zero the full top/bottom padded rows of this n
    if (h == 0) {
        unsigned short* r0 = xq + ((size_t)(n * HP + 0) * WP) * CI;
        for (int i = threadIdx.x; i < WP * CI; i += 256) r0[i] = 0;
    }
    if (h == HH - 1) {
        unsigned short* r65 = xq + ((size_t)(n * HP + (HP - 1)) * WP) * CI;
        for (int i = threadIdx.x; i < WP * CI; i += 256) r65[i] = 0;
    }
}

// ---- 4) implicit-GEMM conv: 3-deep pipeline, 4 LDS buffers, 1 barrier/step ----
__launch_bounds__(256, 2)
__global__ void k_conv(const unsigned short* __restrict__ xq,
                       const unsigned short* __restrict__ wsum,
                       float* __restrict__ out) {
    __shared__ __align__(16) unsigned short lA[4][BM * BK];  // 4 x 8 KB
    __shared__ __align__(16) unsigned short lB[4][BN * BK];  // 4 x 8 KB

    // XCD-chunked swizzle (T1): 64 consecutive logical tiles per XCD
    // (one image's xq slice ~2.2 MB + wsum 1.1 MB fits the 4 MB XCD L2)
    int bx = ((blockIdx.x & 7) << 6) | (blockIdx.x >> 3);
    int pt = bx >> 1, ot = bx & 1;
    int pb = pt * BM;                  // first pixel (n*4096 + h*64 + w)
    int n = pb >> 12;
    int h0 = (pb >> 6) & 63;           // even; LDS rows 0..63 -> h0, 64..127 -> h0+1
    int oc0 = ot * BN;
    int tid = threadIdx.x;

    int base0 = (n * HP + h0) * WP * CI;   // A base (padded coords), + (kh*WP+kw)*CI per tap
    int bBase0 = oc0 * CI;

    // staging: chunk q in [0,512): row=q>>2, s'=q&3, fetch global slot = s'^((row>>1)&3)
    int aOff[2], bOff[2];
    #pragma unroll
    for (int k = 0; k < 2; ++k) {
        int q = tid + k * 256;
        int row = q >> 2, sp = q & 3;
        int slot = sp ^ ((row >> 1) & 3);
        aOff[k] = (((row >> 6) * WP) + (row & 63)) * CI + slot * 8;
        bOff[k] = row * CI + slot * 8;
    }
    // fragment LDS offsets (elems): row r, kslot g lives at s' = g ^ ((r>>1)&3)
    int lane = tid & 63, wid = tid >> 6;
    int wy = wid & 1, wx = wid >> 1;
    int g = lane >> 4, r16 = lane & 15;
    int fA[4], fB[4];
    #pragma unroll
    for (int m = 0; m < 4; ++m) {
        int ra = wy * 64 + m * 16 + r16;
        fA[m] = ra * BK + (g ^ ((ra >> 1) & 3)) * 8;
        int rb = wx * 64 + m * 16 + r16;
        fB[m] = rb * BK + (g ^ ((rb >> 1) & 3)) * 8;
    }

    f32x4 acc[4][4] = {};

    auto stage = [&](int t) {
        int buf = t & 3;
        int tap = t >> 3;
        int c0 = (t & 7) << 5;
        int kh = (tap * 171) >> 9;         // tap/3 for tap in [0,9)
        int kw = tap - kh * 3;
        const unsigned short* aSrc = xq + base0 + (kh * WP + kw) * CI + c0;
        const unsigned short* bSrc = wsum + tap * (OC * CI) + bBase0 + c0;
        #pragma unroll
        for (int k = 0; k < 2; ++k) {
            int q = tid + k * 256;
            __builtin_amdgcn_global_load_lds(
                (const __attribute__((address_space(1))) void*)(aSrc + aOff[k]),
                (__attribute__((address_space(3))) void*)(&lA[buf][q * 8]), 16, 0, 0);
            __builtin_amdgcn_global_load_lds(
                (const __attribute__((address_space(1))) void*)(bSrc + bOff[k]),
                (__attribute__((address_space(3))) void*)(&lB[buf][q * 8]), 16, 0, 0);
        }
    };

    auto compute = [&](int t) {
        int buf = t & 3;
        s16x8 af[4], bfr[4];
        #pragma unroll
        for (int m = 0; m < 4; ++m) af[m] = *(const s16x8*)&lA[buf][fA[m]];
        #pragma unroll
        for (int m = 0; m < 4; ++m) bfr[m] = *(const s16x8*)&lB[buf][fB[m]];
        #pragma unroll
        for (int m = 0; m < 4; ++m)
            #pragma unroll
            for (int nn = 0; nn < 4; ++nn)
                acc[m][nn] = __builtin_amdgcn_mfma_f32_16x16x32_bf16(
                    af[m], bfr[nn], acc[m][nn], 0, 0, 0);
    };

    // prologue: 3 tiles in flight (12 loads/thread)
    stage(0); stage(1); stage(2);
    #pragma unroll 1
    for (int t = 0; t < NT; ++t) {
        int rem = NT - 1 - t;
        // per-thread: 4 loads/tile, in-order completion; wait for tile t's 4
        if (rem >= 2)      asm volatile("s_waitcnt vmcnt(8)" ::: "memory");
        else if (rem == 1) asm volatile("s_waitcnt vmcnt(4)" ::: "memory");
        else               asm volatile("s_waitcnt vmcnt(0)" ::: "memory");
        __builtin_amdgcn_s_barrier();
        // all waves finished compute(t-1) -> buf[(t+3)&3] == buf[(t-1)&3] is free
        if (t + 3 < NT) stage(t + 3);
        compute(t);
    }

    // epilogue: C/D 16x16: col=lane&15 (oc), row=(lane>>4)*4+reg (pixel)
    int hw0 = pb & 4095;
    #pragma unroll
    for (int m = 0; m < 4; ++m) {
        int pl = wy * 64 + m * 16 + g * 4;
        #pragma unroll
        for (int nn = 0; nn < 4; ++nn) {
            int oc = oc0 + wx * 64 + nn * 16 + r16;
            float4 v;
            v.x = acc[m][nn][0]; v.y = acc[m][nn][1];
            v.z = acc[m][nn][2]; v.w = acc[m][nn][3];
            *(float4*)(out + ((size_t)(n * OC + oc) << 12) + hw0 + pl) = v;
        }
    }
}

extern "C" void kernel_launch(void* const* d_in, const int* in_sizes, int n_in,
                              void* d_out, int out_size, void* d_ws, size_t ws_size,
                              hipStream_t stream) {
    (void)in_sizes; (void)n_in; (void)out_size; (void)ws_size;
    const float* x   = (const float*)d_in[0];
    const float* wts = (const float*)d_in[1];
    float* out = (float*)d_out;
    char* wsb = (char*)d_ws;
    float* part            = (float*)wsb;                 // 320 floats
    unsigned short* wsum   = (unsigned short*)(wsb + 4096);          // 9*256*256 bf16 = 1.125 MiB
    unsigned short* xq     = (unsigned short*)(wsb + (size_t)(2u << 20)); // 8*66*66*256 bf16 ~ 17 MiB

    hipLaunchKernelGGL(k_abs_partial, dim3(NBASES * 64), dim3(256), 0, stream, wts, part);
    hipLaunchKernelGGL(k_wsum,        dim3(OC),          dim3(256), 0, stream, wts, part, wsum);
    hipLaunchKernelGGL(k_quant,       dim3(NB * HH),     dim3(256), 0, stream, x, xq);
    hipLaunchKernelGGL(k_conv, dim3((NB * HH * WW / BM) * (OC / BN)), dim3(256), 0, stream,
                       xq, wsum, out);
}

// Round 4
// 80.470 us; speedup vs baseline: 1.1122x; 1.0352x over previous
//
#include <hip/hip_runtime.h>
#include <hip/hip_bf16.h>

typedef __attribute__((ext_vector_type(8))) short s16x8;
typedef __attribute__((ext_vector_type(4))) float f32x4;

constexpr int NB = 8, CI = 256, OC = 256, HH = 64, WW = 64, HP = 66, WP = 66;
constexpr int NBASES = 5;
constexpr int WELEMS = OC * CI * 9;      // 589824 per basis
constexpr int BM = 128, BN = 64, BK = 32;
constexpr int NT = 9 * (CI / BK);        // 72 K-steps (tap-major, then channel chunk)

static __device__ __forceinline__ unsigned short f2bf(float f) {
    unsigned int u = __builtin_bit_cast(unsigned int, f);
    unsigned int r = (u + 0x7fffu + ((u >> 16) & 1u)) >> 16;   // RNE
    return (unsigned short)r;
}

// ---- 1) per-basis partial sums of |w| : grid 5*64, block 256 ----
__global__ void k_abs_partial(const float* __restrict__ w, float* __restrict__ part) {
    int b = blockIdx.x >> 6, chunk = blockIdx.x & 63;
    const float4* v = (const float4*)(w + (size_t)b * WELEMS + (size_t)chunk * (WELEMS / 64));
    float s = 0.f;
    for (int i = threadIdx.x; i < WELEMS / 64 / 4; i += 256) {
        float4 t = v[i];
        s += fabsf(t.x) + fabsf(t.y) + fabsf(t.z) + fabsf(t.w);
    }
    #pragma unroll
    for (int off = 32; off; off >>= 1) s += __shfl_down(s, off, 64);
    __shared__ float ls[4];
    int lane = threadIdx.x & 63, wid = threadIdx.x >> 6;
    if (lane == 0) ls[wid] = s;
    __syncthreads();
    if (threadIdx.x == 0) part[blockIdx.x] = ls[0] + ls[1] + ls[2] + ls[3];
}

// ---- 2) fused prep: blocks [0,256) build wsum; blocks [256,768) quantize x ----
__global__ void k_prep(const float* __restrict__ w, const float* __restrict__ part,
                       unsigned short* __restrict__ wsum,
                       const float* __restrict__ x, unsigned short* __restrict__ xq) {
    __shared__ unsigned short tile[64][264];   // quant branch (16B-aligned rows)
    __shared__ float sLDS[NBASES];             // wsum branch
    int tid = threadIdx.x;

    if (blockIdx.x < OC) {
        // ---- wsum[tap][o][i] = (1/5) * sum_b sign(w[b,o,i,tap])*s_b ----
        if (tid < 64) {
            #pragma unroll
            for (int b = 0; b < NBASES; ++b) {
                float v = part[b * 64 + tid];
                #pragma unroll
                for (int off = 32; off; off >>= 1) v += __shfl_down(v, off, 64);
                if (tid == 0) sLDS[b] = v * (1.0f / (float)WELEMS);
            }
        }
        __syncthreads();
        float sc[NBASES];
        #pragma unroll
        for (int b = 0; b < NBASES; ++b) sc[b] = sLDS[b];

        int o = blockIdx.x, i = tid;
        const float* base = w + ((size_t)(o * CI + i)) * 9;
        float acc[9];
        #pragma unroll
        for (int t = 0; t < 9; ++t) acc[t] = 0.f;
        #pragma unroll
        for (int b = 0; b < NBASES; ++b) {
            const float* wb = base + (size_t)b * WELEMS;
            #pragma unroll
            for (int t = 0; t < 9; ++t) {
                float xv = wb[t];
                acc[t] += (xv > 0.f) ? sc[b] : ((xv < 0.f) ? -sc[b] : 0.f);
            }
        }
        #pragma unroll
        for (int t = 0; t < 9; ++t)
            wsum[(t * OC + o) * CI + i] = f2bf(acc[t] * 0.2f);
        return;
    }

    // ---- xq_pad[n][h+1][w+1][c] = bf16(round(clip(x,0,1))), borders 0 ----
    int nh = blockIdx.x - OC, n = nh >> 6, h = nh & 63;
    const float* xb = x + ((size_t)n * CI) * (HH * WW) + h * WW;   // + c*4096 + w
    int tw = tid & 63, tc0 = tid >> 6;
    for (int c = tc0; c < CI; c += 4) {
        float v = xb[(size_t)c * (HH * WW) + tw];
        v = rintf(fminf(fmaxf(v, 0.f), 1.f));
        tile[tw][c] = f2bf(v);
    }
    __syncthreads();
    unsigned short* ob = xq + ((size_t)(n * HP + (h + 1)) * WP + 1) * CI;
    int wq = tid >> 5;            // 0..7
    int cq = (tid & 31) * 8;      // 0..248
    #pragma unroll
    for (int i = 0; i < 8; ++i) {
        int wv = i * 8 + wq;
        s16x8 v = *(const s16x8*)&tile[wv][cq];
        *(s16x8*)(ob + wv * CI + cq) = v;
    }
    (ob - CI)[tid] = 0;
    (ob + 64 * CI)[tid] = 0;
    if (h == 0) {
        unsigned short* r0 = xq + ((size_t)(n * HP + 0) * WP) * CI;
        for (int i = tid; i < WP * CI; i += 256) r0[i] = 0;
    }
    if (h == HH - 1) {
        unsigned short* r65 = xq + ((size_t)(n * HP + (HP - 1)) * WP) * CI;
        for (int i = tid; i < WP * CI; i += 256) r65[i] = 0;
    }
}

// ---- 3) implicit-GEMM conv: 1024 blocks x 2 waves, 4 blocks/CU, 3-buf pipeline ----
__launch_bounds__(128, 2)
__global__ void k_conv(const unsigned short* __restrict__ xq,
                       const unsigned short* __restrict__ wsum,
                       float* __restrict__ out) {
    __shared__ __align__(16) unsigned short lA[3][BM * BK];  // 3 x 8 KB
    __shared__ __align__(16) unsigned short lB[3][BN * BK];  // 3 x 4 KB

    // XCD-chunked swizzle: 1024 blocks, 128 consecutive logical tiles per XCD
    // (= 32 M-tiles x all 4 N-tiles: shares wsum 1.1 MB + ~2.2 MB xq slice in L2)
    int bid = blockIdx.x;
    int bx = ((bid & 7) << 7) | (bid >> 3);
    int pt = bx >> 2, ot = bx & 3;
    int pb = pt * BM;                  // first pixel (n*4096 + h*64 + w)
    int n = pb >> 12;
    int h0 = (pb >> 6) & 63;           // even; LDS rows 0..63 -> h0, 64..127 -> h0+1
    int oc0 = ot * BN;
    int tid = threadIdx.x;

    int base0 = (n * HP + h0) * WP * CI;
    int bBase0 = oc0 * CI;

    // staging offsets: chunk q: row=q>>2, s'=q&3, fetch global slot = s'^((row>>1)&3)
    int aOff[4], bOff[2];
    #pragma unroll
    for (int k = 0; k < 4; ++k) {
        int q = tid + k * 128;         // q in [0,512): A = 128 rows x 4 slots
        int row = q >> 2, sp = q & 3;
        int slot = sp ^ ((row >> 1) & 3);
        aOff[k] = (((row >> 6) * WP) + (row & 63)) * CI + slot * 8;
    }
    #pragma unroll
    for (int k = 0; k < 2; ++k) {
        int q = tid + k * 128;         // q in [0,256): B = 64 rows x 4 slots
        int row = q >> 2, sp = q & 3;
        int slot = sp ^ ((row >> 1) & 3);
        bOff[k] = row * CI + slot * 8;
    }
    // fragment LDS offsets: row r, kslot g lives at s' = g ^ ((r>>1)&3)
    int lane = tid & 63, wv = tid >> 6;     // wv in {0,1}: pixel half
    int g = lane >> 4, r16 = lane & 15;
    int fA[4], fB[4];
    #pragma unroll
    for (int m = 0; m < 4; ++m) {
        int ra = wv * 64 + m * 16 + r16;
        fA[m] = ra * BK + (g ^ ((ra >> 1) & 3)) * 8;
        int rb = m * 16 + r16;
        fB[m] = rb * BK + (g ^ ((rb >> 1) & 3)) * 8;
    }

    f32x4 acc[4][4] = {};

    auto stage = [&](int t) {
        int buf = t % 3;
        int tap = t >> 3;
        int c0 = (t & 7) << 5;
        int kh = (tap * 171) >> 9;         // tap/3 for tap in [0,9)
        int kw = tap - kh * 3;
        const unsigned short* aSrc = xq + base0 + (kh * WP + kw) * CI + c0;
        const unsigned short* bSrc = wsum + tap * (OC * CI) + bBase0 + c0;
        #pragma unroll
        for (int k = 0; k < 4; ++k)
            __builtin_amdgcn_global_load_lds(
                (const __attribute__((address_space(1))) void*)(aSrc + aOff[k]),
                (__attribute__((address_space(3))) void*)(&lA[buf][(tid + k * 128) * 8]), 16, 0, 0);
        #pragma unroll
        for (int k = 0; k < 2; ++k)
            __builtin_amdgcn_global_load_lds(
                (const __attribute__((address_space(1))) void*)(bSrc + bOff[k]),
                (__attribute__((address_space(3))) void*)(&lB[buf][(tid + k * 128) * 8]), 16, 0, 0);
    };

    auto compute = [&](int t) {
        int buf = t % 3;
        s16x8 af[4], bfr[4];
        #pragma unroll
        for (int m = 0; m < 4; ++m) af[m] = *(const s16x8*)&lA[buf][fA[m]];
        #pragma unroll
        for (int m = 0; m < 4; ++m) bfr[m] = *(const s16x8*)&lB[buf][fB[m]];
        __builtin_amdgcn_s_setprio(1);
        #pragma unroll
        for (int m = 0; m < 4; ++m)
            #pragma unroll
            for (int nn = 0; nn < 4; ++nn)
                acc[m][nn] = __builtin_amdgcn_mfma_f32_16x16x32_bf16(
                    af[m], bfr[nn], acc[m][nn], 0, 0, 0);
        __builtin_amdgcn_s_setprio(0);
    };

    // prologue: 2 tiles in flight (12 loads/thread)
    stage(0); stage(1);
    #pragma unroll 1
    for (int t = 0; t < NT; ++t) {
        // per-thread 6 loads/tile, in-order completion
        if (t < NT - 1) asm volatile("s_waitcnt vmcnt(6)" ::: "memory");
        else            asm volatile("s_waitcnt vmcnt(0)" ::: "memory");
        __builtin_amdgcn_s_barrier();
        // both waves finished compute(t-1) -> buf[(t+2)%3] == buf[(t-1)%3] is free
        if (t + 2 < NT) stage(t + 2);
        compute(t);
    }

    // epilogue: C/D 16x16: col=lane&15 (oc), row=(lane>>4)*4+reg (pixel)
    int hw0 = pb & 4095;
    #pragma unroll
    for (int m = 0; m < 4; ++m) {
        int pl = wv * 64 + m * 16 + g * 4;
        #pragma unroll
        for (int nn = 0; nn < 4; ++nn) {
            int oc = oc0 + nn * 16 + r16;
            float4 v;
            v.x = acc[m][nn][0]; v.y = acc[m][nn][1];
            v.z = acc[m][nn][2]; v.w = acc[m][nn][3];
            *(float4*)(out + ((size_t)(n * OC + oc) << 12) + hw0 + pl) = v;
        }
    }
}

extern "C" void kernel_launch(void* const* d_in, const int* in_sizes, int n_in,
                              void* d_out, int out_size, void* d_ws, size_t ws_size,
                              hipStream_t stream) {
    (void)in_sizes; (void)n_in; (void)out_size; (void)ws_size;
    const float* x   = (const float*)d_in[0];
    const float* wts = (const float*)d_in[1];
    float* out = (float*)d_out;
    char* wsb = (char*)d_ws;
    float* part            = (float*)wsb;                 // 320 floats
    unsigned short* wsum   = (unsigned short*)(wsb + 4096);          // 9*256*256 bf16 = 1.125 MiB
    unsigned short* xq     = (unsigned short*)(wsb + (size_t)(2u << 20)); // 8*66*66*256 bf16 ~ 17 MiB

    hipLaunchKernelGGL(k_abs_partial, dim3(NBASES * 64), dim3(256), 0, stream, wts, part);
    hipLaunchKernelGGL(k_prep, dim3(OC + NB * HH), dim3(256), 0, stream,
                       wts, part, wsum, x, xq);
    hipLaunchKernelGGL(k_conv, dim3((NB * HH * WW / BM) * (OC / BN)), dim3(128), 0, stream,
                       xq, wsum, out);
}

// Round 5
// 64.605 us; speedup vs baseline: 1.3853x; 1.2456x over previous
//
#include <hip/hip_runtime.h>
#include <hip/hip_bf16.h>

typedef __attribute__((ext_vector_type(8))) short s16x8;
typedef __attribute__((ext_vector_type(4))) float f32x4;

constexpr int NB = 8, CI = 256, OC = 256, HH = 64, WW = 64, HP = 66, WP = 66;
constexpr int NBASES = 5;
constexpr int WELEMS = OC * CI * 9;      // 589824 per basis
constexpr int BM = 256, BN = 128, BK = 64;
constexpr int NT = 9 * (CI / BK);        // 36 K-steps (tap-major, then 64-ch chunk)

static __device__ __forceinline__ unsigned short f2bf(float f) {
    unsigned int u = __builtin_bit_cast(unsigned int, f);
    unsigned int r = (u + 0x7fffu + ((u >> 16) & 1u)) >> 16;   // RNE
    return (unsigned short)r;
}

// ---- 1) per-basis partial sums of |w| : grid 5*64, block 256 ----
__global__ void k_abs_partial(const float* __restrict__ w, float* __restrict__ part) {
    int b = blockIdx.x >> 6, chunk = blockIdx.x & 63;
    const float4* v = (const float4*)(w + (size_t)b * WELEMS + (size_t)chunk * (WELEMS / 64));
    float s = 0.f;
    for (int i = threadIdx.x; i < WELEMS / 64 / 4; i += 256) {
        float4 t = v[i];
        s += fabsf(t.x) + fabsf(t.y) + fabsf(t.z) + fabsf(t.w);
    }
    #pragma unroll
    for (int off = 32; off; off >>= 1) s += __shfl_down(s, off, 64);
    __shared__ float ls[4];
    int lane = threadIdx.x & 63, wid = threadIdx.x >> 6;
    if (lane == 0) ls[wid] = s;
    __syncthreads();
    if (threadIdx.x == 0) part[blockIdx.x] = ls[0] + ls[1] + ls[2] + ls[3];
}

// ---- 2) fused prep: blocks [0,256) build wsum; blocks [256,768) quantize x ----
__global__ void k_prep(const float* __restrict__ w, const float* __restrict__ part,
                       unsigned short* __restrict__ wsum,
                       const float* __restrict__ x, unsigned short* __restrict__ xq) {
    __shared__ unsigned short tile[64][264];   // quant branch (16B-aligned rows)
    __shared__ float sLDS[NBASES];             // wsum branch
    int tid = threadIdx.x;

    if (blockIdx.x < OC) {
        // ---- wsum[tap][o][i] = (1/5) * sum_b sign(w[b,o,i,tap])*s_b ----
        if (tid < 64) {
            #pragma unroll
            for (int b = 0; b < NBASES; ++b) {
                float v = part[b * 64 + tid];
                #pragma unroll
                for (int off = 32; off; off >>= 1) v += __shfl_down(v, off, 64);
                if (tid == 0) sLDS[b] = v * (1.0f / (float)WELEMS);
            }
        }
        __syncthreads();
        float sc[NBASES];
        #pragma unroll
        for (int b = 0; b < NBASES; ++b) sc[b] = sLDS[b];

        int o = blockIdx.x, i = tid;
        const float* base = w + ((size_t)(o * CI + i)) * 9;
        float acc[9];
        #pragma unroll
        for (int t = 0; t < 9; ++t) acc[t] = 0.f;
        #pragma unroll
        for (int b = 0; b < NBASES; ++b) {
            const float* wb = base + (size_t)b * WELEMS;
            #pragma unroll
            for (int t = 0; t < 9; ++t) {
                float xv = wb[t];
                acc[t] += (xv > 0.f) ? sc[b] : ((xv < 0.f) ? -sc[b] : 0.f);
            }
        }
        #pragma unroll
        for (int t = 0; t < 9; ++t)
            wsum[(t * OC + o) * CI + i] = f2bf(acc[t] * 0.2f);
        return;
    }

    // ---- xq_pad[n][h+1][w+1][c] = bf16(round(clip(x,0,1))), borders 0 ----
    int nh = blockIdx.x - OC, n = nh >> 6, h = nh & 63;
    const float* xb = x + ((size_t)n * CI) * (HH * WW) + h * WW;   // + c*4096 + w
    int tw = tid & 63, tc0 = tid >> 6;
    for (int c = tc0; c < CI; c += 4) {
        float v = xb[(size_t)c * (HH * WW) + tw];
        v = rintf(fminf(fmaxf(v, 0.f), 1.f));
        tile[tw][c] = f2bf(v);
    }
    __syncthreads();
    unsigned short* ob = xq + ((size_t)(n * HP + (h + 1)) * WP + 1) * CI;
    int wq = tid >> 5;            // 0..7
    int cq = (tid & 31) * 8;      // 0..248
    #pragma unroll
    for (int i = 0; i < 8; ++i) {
        int wv = i * 8 + wq;
        s16x8 v = *(const s16x8*)&tile[wv][cq];
        *(s16x8*)(ob + wv * CI + cq) = v;
    }
    (ob - CI)[tid] = 0;
    (ob + 64 * CI)[tid] = 0;
    if (h == 0) {
        unsigned short* r0 = xq + ((size_t)(n * HP + 0) * WP) * CI;
        for (int i = tid; i < WP * CI; i += 256) r0[i] = 0;
    }
    if (h == HH - 1) {
        unsigned short* r65 = xq + ((size_t)(n * HP + (HP - 1)) * WP) * CI;
        for (int i = tid; i < WP * CI; i += 256) r65[i] = 0;
    }
}

// ---- 3) conv: m201-style template. 256x128 tile, BK=64, 8 waves, 3-buf LDS,
//         2 phases x 16 MFMA per K-step, counted vmcnt(6), setprio ----
__launch_bounds__(512, 2)
__global__ void k_conv(const unsigned short* __restrict__ xq,
                       const unsigned short* __restrict__ wsum,
                       float* __restrict__ out) {
    __shared__ __align__(16) unsigned short lA[3][BM * BK];  // 3 x 32 KB
    __shared__ __align__(16) unsigned short lB[3][BN * BK];  // 3 x 16 KB

    // XCD-chunked swizzle: 256 blocks, 32 logical tiles per XCD
    // (= 16 M-tiles x 2 N-tiles = one image x all oc: ~2.2 MB xq + 1.1 MB wsum in L2)
    int bid = blockIdx.x;
    int bx = ((bid & 7) << 5) | (bid >> 3);
    int pt = bx >> 1, ot = bx & 1;
    int pb = pt * BM;                  // first pixel (n*4096 + h*64 + w)
    int n = pb >> 12;
    int h0 = (pb >> 6) & 63;           // rows 0..63 -> h0 .. rows 192..255 -> h0+3
    int oc0 = ot * BN;
    int tid = threadIdx.x;

    int base0 = (n * HP + h0) * WP * CI;
    int bBase0 = oc0 * CI;

    // staging: chunk c: row=c>>3, sp=c&7, fetch global slot = sp^(row&7)
    // (linear LDS dest + inverse-swizzled global source; read applies same XOR)
    int aOff[4], bOff[2];
    #pragma unroll
    for (int k = 0; k < 4; ++k) {
        int c = tid + k * 512;              // A: 256 rows x 8 slots = 2048 chunks
        int row = c >> 3, sp = c & 7;
        int slot = sp ^ (row & 7);
        aOff[k] = ((row >> 6) * WP + (row & 63)) * CI + slot * 8;
    }
    #pragma unroll
    for (int k = 0; k < 2; ++k) {
        int c = tid + k * 512;              // B: 128 rows x 8 slots = 1024 chunks
        int row = c >> 3, sp = c & 7;
        int slot = sp ^ (row & 7);
        bOff[k] = row * CI + slot * 8;
    }

    int lane = tid & 63, wid = tid >> 6;
    int wm = wid >> 1, wn = wid & 1;        // 4M x 2N wave grid, 64x64 per wave
    int g = lane >> 4, r16 = lane & 15;
    // logical k-slot for kk-half: kk*4+g ; physical slot = logical ^ (r16&7)
    int slot0 = (g) ^ (r16 & 7);
    int slot1 = (4 + g) ^ (r16 & 7);
    int aRow = (wm * 64 + r16) * BK;        // elem offset of frag row base in A tile
    int bRow = (wn * 64 + r16) * BK;

    f32x4 acc[4][4] = {};
    s16x8 bR[4][2];                          // B frags cached across both phases

    auto stage = [&](int t, int half) {
        int buf = t % 3;
        int tap = t >> 2;
        int c0 = (t & 3) << 6;
        int kh = (tap * 171) >> 9;          // tap/3 for tap in [0,9)
        int kw = tap - kh * 3;
        const unsigned short* aSrc = xq + base0 + (kh * WP + kw) * CI + c0;
        const unsigned short* bSrc = wsum + tap * (OC * CI) + bBase0 + c0;
        #pragma unroll
        for (int k = half * 2; k < half * 2 + 2; ++k)
            __builtin_amdgcn_global_load_lds(
                (const __attribute__((address_space(1))) void*)(aSrc + aOff[k]),
                (__attribute__((address_space(3))) void*)(&lA[buf][(tid + k * 512) * 8]), 16, 0, 0);
        __builtin_amdgcn_global_load_lds(
            (const __attribute__((address_space(1))) void*)(bSrc + bOff[half]),
            (__attribute__((address_space(3))) void*)(&lB[buf][(tid + half * 512) * 8]), 16, 0, 0);
    };

    // prologue: 2 K-steps in flight (12 loads/thread)
    stage(0, 0); stage(0, 1); stage(1, 0); stage(1, 1);

    #pragma unroll 1
    for (int t = 0; t < NT; ++t) {
        int buf = t % 3;
        const unsigned short* A  = &lA[buf][aRow];
        const unsigned short* Bb = &lB[buf][bRow];
        // counted wait: my 6 loads for step t are the oldest; t+1's 6 stay in flight
        if (t < NT - 1) asm volatile("s_waitcnt vmcnt(6)" ::: "memory");
        else            asm volatile("s_waitcnt vmcnt(0)" ::: "memory");
        __builtin_amdgcn_s_barrier();

        // ---- phase A: 12 ds_read + 3 stage-issues + 16 MFMA (acc[0..1][*]) ----
        s16x8 aR[2][2];
        #pragma unroll
        for (int mq = 0; mq < 2; ++mq) {
            aR[mq][0] = *(const s16x8*)(A + mq * 16 * BK + slot0 * 8);
            aR[mq][1] = *(const s16x8*)(A + mq * 16 * BK + slot1 * 8);
        }
        #pragma unroll
        for (int nq = 0; nq < 4; ++nq) {
            bR[nq][0] = *(const s16x8*)(Bb + nq * 16 * BK + slot0 * 8);
            bR[nq][1] = *(const s16x8*)(Bb + nq * 16 * BK + slot1 * 8);
        }
        if (t + 2 < NT) stage(t + 2, 0);
        asm volatile("s_waitcnt lgkmcnt(0)" ::: "memory");
        __builtin_amdgcn_s_setprio(1);
        #pragma unroll
        for (int mq = 0; mq < 2; ++mq)
            #pragma unroll
            for (int nq = 0; nq < 4; ++nq) {
                acc[mq][nq] = __builtin_amdgcn_mfma_f32_16x16x32_bf16(
                    aR[mq][0], bR[nq][0], acc[mq][nq], 0, 0, 0);
                acc[mq][nq] = __builtin_amdgcn_mfma_f32_16x16x32_bf16(
                    aR[mq][1], bR[nq][1], acc[mq][nq], 0, 0, 0);
            }
        __builtin_amdgcn_s_setprio(0);
        asm volatile("s_barrier" ::: "memory");

        // ---- phase B: 4 ds_read (B reused in regs) + 3 stage-issues + 16 MFMA ----
        #pragma unroll
        for (int mq = 0; mq < 2; ++mq) {
            aR[mq][0] = *(const s16x8*)(A + (mq + 2) * 16 * BK + slot0 * 8);
            aR[mq][1] = *(const s16x8*)(A + (mq + 2) * 16 * BK + slot1 * 8);
        }
        if (t + 2 < NT) stage(t + 2, 1);
        asm volatile("s_waitcnt lgkmcnt(0)" ::: "memory");
        __builtin_amdgcn_s_setprio(1);
        #pragma unroll
        for (int mq = 0; mq < 2; ++mq)
            #pragma unroll
            for (int nq = 0; nq < 4; ++nq) {
                acc[mq + 2][nq] = __builtin_amdgcn_mfma_f32_16x16x32_bf16(
                    aR[mq][0], bR[nq][0], acc[mq + 2][nq], 0, 0, 0);
                acc[mq + 2][nq] = __builtin_amdgcn_mfma_f32_16x16x32_bf16(
                    aR[mq][1], bR[nq][1], acc[mq + 2][nq], 0, 0, 0);
            }
        __builtin_amdgcn_s_setprio(0);
        // no trailing barrier: next iter leads with vmcnt + barrier
    }

    // epilogue: C/D 16x16: col=lane&15 (oc), row=(lane>>4)*4+reg (pixel)
    int hw0 = pb & 4095;
    #pragma unroll
    for (int mq = 0; mq < 4; ++mq) {
        int pl = wm * 64 + mq * 16 + g * 4;
        #pragma unroll
        for (int nq = 0; nq < 4; ++nq) {
            int oc = oc0 + wn * 64 + nq * 16 + r16;
            float4 v;
            v.x = acc[mq][nq][0]; v.y = acc[mq][nq][1];
            v.z = acc[mq][nq][2]; v.w = acc[mq][nq][3];
            *(float4*)(out + ((size_t)(n * OC + oc) << 12) + hw0 + pl) = v;
        }
    }
}

extern "C" void kernel_launch(void* const* d_in, const int* in_sizes, int n_in,
                              void* d_out, int out_size, void* d_ws, size_t ws_size,
                              hipStream_t stream) {
    (void)in_sizes; (void)n_in; (void)out_size; (void)ws_size;
    const float* x   = (const float*)d_in[0];
    const float* wts = (const float*)d_in[1];
    float* out = (float*)d_out;
    char* wsb = (char*)d_ws;
    float* part            = (float*)wsb;                 // 320 floats
    unsigned short* wsum   = (unsigned short*)(wsb + 4096);          // 9*256*256 bf16 = 1.125 MiB
    unsigned short* xq     = (unsigned short*)(wsb + (size_t)(2u << 20)); // 8*66*66*256 bf16 ~ 17 MiB

    hipLaunchKernelGGL(k_abs_partial, dim3(NBASES * 64), dim3(256), 0, stream, wts, part);
    hipLaunchKernelGGL(k_prep, dim3(OC + NB * HH), dim3(256), 0, stream,
                       wts, part, wsum, x, xq);
    hipLaunchKernelGGL(k_conv, dim3((NB * HH * WW / BM) * (OC / BN)), dim3(512), 0, stream,
                       xq, wsum, out);
}